// Round 5
// baseline (5856.496 us; speedup 1.0000x reference)
//
#include <hip/hip_runtime.h>

#define LSEQ 96
#define DM 256
#define NH 8
#define DH 32
#define WIN 16
#define NW 33   /* 2*WIN+1 allowed keys per query */
#define PSTRIDE 34

typedef unsigned short u16;
typedef unsigned int u32;

// One block per sequence n. 512 threads. fp32 inputs, fp32 math, fp32 out.
// Entire attention + output projection fused; d_ws deliberately unused.
__global__ __launch_bounds__(512) void fused_attn_kernel(
    const float* __restrict__ Z,  const float* __restrict__ Wq,
    const float* __restrict__ Wk, const float* __restrict__ Wv,
    const float* __restrict__ Wo, const float* __restrict__ rb,
    float* __restrict__ out)
{
    __shared__ float qkv[3 * LSEQ * DH];      // 36864 B: q,k,v for current head
    __shared__ float probs[LSEQ * PSTRIDE];   // 13056 B
    __shared__ float attnh[LSEQ * DH];        // 12288 B: P@V for current head
    // total 62208 B

    const int tid = threadIdx.x;
    const int n = blockIdx.x;
    const float* __restrict__ Xn = Z + (size_t)n * (LSEQ * DM);

    float oacc[48];
#pragma unroll
    for (int r = 0; r < 48; ++r) oacc[r] = 0.f;

    const float scale = 0.17677669529663687f;  // 1/sqrt(32)

    for (int h = 0; h < NH; ++h) {
        __syncthreads();  // protect qkv/probs/attnh reuse across head iterations

        // ---- QKV: 3*96*32 = 9216 tasks, each a 256-length dot ----
        for (int r = 0; r < 18; ++r) {
            int u = tid + (r << 9);
            int which = u / 3072;              // 0=q, 1=k, 2=v
            int rem = u - which * 3072;
            int l = rem >> 5;
            int c = rem & 31;
            const float* W = (which == 0) ? Wq : (which == 1) ? Wk : Wv;
            const float* wp = W + h * DH + c;  // column (h*32+c), stride 256
            const float* xr = Xn + l * DM;
            float acc = 0.f;
            for (int d = 0; d < DM; ++d)
                acc += xr[d] * wp[(size_t)d * 256];
            qkv[which * 3072 + l * DH + c] = acc;
        }
        __syncthreads();

        const float* qs = qkv;
        const float* ks = qkv + 3072;
        const float* vs = qkv + 6144;

        // ---- windowed logits: 96 x 33, + circular relative bias ----
        for (int t = tid; t < LSEQ * NW; t += 512) {
            int i = t / NW;
            int jj = t - i * NW;
            int j = i - WIN + jj;
            if (j < 0) j += LSEQ;
            else if (j >= LSEQ) j -= LSEQ;
            float dot = 0.f;
            for (int d = 0; d < DH; ++d)
                dot += qs[i * DH + d] * ks[j * DH + d];
            // rel = (i - j) mod L = (WIN - jj) mod L
            int rr = (jj <= WIN) ? (WIN - jj) : (LSEQ + WIN - jj);
            probs[i * PSTRIDE + jj] = dot * scale + rb[h * LSEQ + rr];
        }
        __syncthreads();

        // ---- softmax over the 33 allowed entries, one thread per row ----
        if (tid < LSEQ) {
            float* row = probs + tid * PSTRIDE;
            float m = row[0];
            for (int jj = 1; jj < NW; ++jj) m = fmaxf(m, row[jj]);
            float s = 0.f;
            for (int jj = 0; jj < NW; ++jj) {
                float e = __expf(row[jj] - m);
                row[jj] = e;
                s += e;
            }
            float inv = 1.f / s;
            for (int jj = 0; jj < NW; ++jj) row[jj] *= inv;
        }
        __syncthreads();

        // ---- attnh = P @ V (96 x 32) ----
        for (int r = 0; r < 6; ++r) {
            int o = tid + (r << 9);
            int l = o >> 5;
            int c = o & 31;
            const float* row = probs + l * PSTRIDE;
            float s = 0.f;
            int j = l - WIN;
            if (j < 0) j += LSEQ;
            for (int jj = 0; jj < NW; ++jj) {
                s += row[jj] * vs[j * DH + c];
                if (++j >= LSEQ) j = 0;
            }
            attnh[l * DH + c] = s;
        }
        __syncthreads();

        // ---- accumulate attnh @ Wo[h*32:(h+1)*32, :] into registers ----
        for (int r = 0; r < 48; ++r) {
            int o = tid + (r << 9);          // o = l*256 + dcol, covers 96*256
            int l = o >> 8;
            int dcol = o & 255;
            const float* wrow = Wo + (size_t)(h * DH) * 256 + dcol;  // stride 256
            const float* ar = attnh + l * DH;
            float s = oacc[r];
            for (int c = 0; c < DH; ++c)
                s += ar[c] * wrow[(size_t)c * 256];
            oacc[r] = s;
        }
    }

    // ---- final store, fp32 ----
    float* on = out + (size_t)n * (LSEQ * DM);
    for (int r = 0; r < 48; ++r) {
        int o = tid + (r << 9);
        on[o] = oacc[r];
    }
}

extern "C" void kernel_launch(void* const* d_in, const int* in_sizes, int n_in,
                              void* d_out, int out_size, void* d_ws, size_t ws_size,
                              hipStream_t stream) {
    const float* Z  = (const float*)d_in[0];
    const float* Wq = (const float*)d_in[1];
    const float* Wk = (const float*)d_in[2];
    const float* Wv = (const float*)d_in[3];
    const float* Wo = (const float*)d_in[4];
    const float* rb = (const float*)d_in[5];
    float* out = (float*)d_out;

    fused_attn_kernel<<<1024, 512, 0, stream>>>(Z, Wq, Wk, Wv, Wo, rb, out);
}